// Round 14
// baseline (4803.797 us; speedup 1.0000x reference)
//
#include <hip/hip_runtime.h>

#define T_TOT 1024
#define BB 64
#define DD 128
#define HH 256
#define GG 1024
#define OO 64
#define LN_EPS 1e-3f
#define NLT 16   // LDS-resident B-tiles per wave (K-tiles 0,1) -> 128KB static
#define NST 48   // streamed B-tiles per wave (K-tiles 2..7), double-buffered

typedef unsigned int u32;
typedef _Float16 h2 __attribute__((ext_vector_type(2)));
typedef _Float16 f16x8 __attribute__((ext_vector_type(8)));
typedef float f32x4 __attribute__((ext_vector_type(4)));

__device__ __forceinline__ float fdot2(u32 a, u32 b, float c) {
  return __builtin_amdgcn_fdot2(__builtin_bit_cast(h2, a), __builtin_bit_cast(h2, b), c, false);
}
__device__ __forceinline__ u32 pkf16(float lo, float hi) {
  h2 v = { (_Float16)lo, (_Float16)hi };
  return __builtin_bit_cast(u32, v);
}
__device__ __forceinline__ float fast_sigmoid(float x) { return 1.0f / (1.0f + __expf(-x)); }
__device__ __forceinline__ float fast_tanh(float x) { return 2.0f / (1.0f + __expf(-2.0f * x)) - 1.0f; }

// A-fragment for K-tile t: lanes with l4==0 carry hx[t*32 + (lane>>4)*8 + j],
// all other lanes zero -> M=1 GEMV on the matrix pipe. (v5-verified layout.)
#define AFRAG(t) \
    uint4 hv = *(const uint4*)(hx16 + (t) * 32 + ((lane >> 4) << 3)); \
    uint4 az; \
    az.x = (l4 == 0) ? hv.x : 0u; az.y = (l4 == 0) ? hv.y : 0u; \
    az.z = (l4 == 0) ? hv.z : 0u; az.w = (l4 == 0) ? hv.w : 0u; \
    f16x8 afr = __builtin_bit_cast(f16x8, az);

// ---- prep: pack Wh (4H x H) into per-wave MFMA B-fragments (v5-verified).
// Tile (w, t, n): B[k][col], col = w*128 + n*16 + (lane&15),
// k = t*32 + (lane>>4)*8 + j (j=0..7). bfragG[(w*64 + t*8+n)*64 + lane].
__global__ void prep_bfrag(const float* __restrict__ Wh, uint4* __restrict__ bfragG) {
  int id = blockIdx.x * 256 + threadIdx.x;     // 32768 slots
  int lane = id & 63, tile = (id >> 6) & 63, w = id >> 12;
  int t = tile >> 3, n = tile & 7;
  int col = w * 128 + n * 16 + (lane & 15);    // gate index g
  int k0 = t * 32 + (lane >> 4) * 8;
  const float* p = Wh + (size_t)col * HH + k0; // Wh[g][k0..k0+7]
  uint4 o;
  o.x = pkf16(p[0], p[1]); o.y = pkf16(p[2], p[3]);
  o.z = pkf16(p[4], p[5]); o.w = pkf16(p[6], p[7]);
  bfragG[id] = o;
}

__global__ void prep_wi(const float* __restrict__ Wi, uint4* __restrict__ wip4) {
  int id = blockIdx.x * 256 + threadIdx.x;     // 16384
  int kp4 = id >> 10, g = id & 1023;
  const float* p = Wi + (size_t)g * DD + kp4 * 8;
  uint4 o;
  o.x = pkf16(p[0], p[1]); o.y = pkf16(p[2], p[3]);
  o.z = pkf16(p[4], p[5]); o.w = pkf16(p[6], p[7]);
  wip4[id] = o;
}

// ---------------- xproj GEMM: writes xph in fragment order:
// row ml, offset (g>>7)*128 + (g&15)*8 + ((g>>4)&7)   (v5-verified)
__global__ __launch_bounds__(256) void xproj_gemm(
    const float* __restrict__ x, const uint4* __restrict__ wip4,
    const float* __restrict__ bi, const float* __restrict__ bh,
    _Float16* __restrict__ xph, int m0) {
  __shared__ _Float16 xl[16][128];
  const int tid = threadIdx.x;
  const int mt = blockIdx.x, gt = blockIdx.y;
  const int g = gt * 256 + tid;
  const int woff = ((g >> 7) << 7) | ((g & 15) << 3) | ((g >> 4) & 7);
#pragma unroll
  for (int i = 0; i < 8; ++i) {
    int idx = i * 256 + tid;          // 0..2047
    int p = idx >> 7, d = idx & 127;
    int m = m0 + mt * 16 + p;         // global m = t*64+b
    xl[p][d] = (_Float16)x[(size_t)(m & 63) * (T_TOT * DD) + (size_t)(m >> 6) * DD + d];
  }
  __syncthreads();
  float acc[16];
#pragma unroll
  for (int p = 0; p < 16; ++p) acc[p] = 0.f;
#pragma unroll
  for (int kp4 = 0; kp4 < 16; ++kp4) {
    uint4 w = wip4[kp4 * GG + g];
#pragma unroll
    for (int p = 0; p < 16; ++p) {
      uint4 hv = *(const uint4*)(&xl[p][kp4 * 8]);   // uniform addr -> broadcast
      acc[p] = fdot2(w.x, hv.x, acc[p]);
      acc[p] = fdot2(w.y, hv.y, acc[p]);
      acc[p] = fdot2(w.z, hv.z, acc[p]);
      acc[p] = fdot2(w.w, hv.w, acc[p]);
    }
  }
  float bsum = bi[g] + bh[g];
#pragma unroll
  for (int p = 0; p < 16; ++p) {
    int ml = mt * 16 + p;
    xph[(size_t)ml * GG + woff] = (_Float16)(acc[p] + bsum);
  }
}

// ---------------- scan v15 (MFMA, zero persistent weight registers):
// 512 threads / 8 waves; wave w owns gates [w*128,(w+1)*128) = 8 N-tiles x
// 8 K-tiles of v_mfma_f32_16x16x32_f16, M=1. B-tiles: K0,K1 from static LDS
// (16/wave), K2..K7 streamed from L2 each step via two 8-tile buffers
// (refilled after consumption -> WAR serialization stops load hoisting).
// Register demand ~126 fits the 128-VGPR grant; no persistent weight arrays
// (the proven failure mode of v5/v7/v13).
__global__ __launch_bounds__(512) void lstm_scan(
    const uint4* __restrict__ bfragG, const _Float16* __restrict__ xphf,
    const float* __restrict__ lna_g, const float* __restrict__ lna_b,
    const float* __restrict__ ln_g, const float* __restrict__ ln_b,
    _Float16* __restrict__ hs16,
    _Float16* __restrict__ hxst, float* __restrict__ cxst,
    int t0, int ct) {
  __shared__ uint4 wl[8 * NLT * 64];       // 131072 B
  __shared__ _Float16 hx16[HH];            // 512 B
  __shared__ float red[16];
  __shared__ float red2[8];
  __shared__ float gact[GG];               // 4096 B -> ~135.8 KB total

  const int tid = threadIdx.x, b = blockIdx.x;
  const int lane = tid & 63, wid = tid >> 6, q = wid >> 1;
  const int l4 = lane & 15;

  const uint4* bw = bfragG + wid * 4096;
#pragma unroll
  for (int i = 0; i < NLT; ++i)
    wl[(wid * NLT + i) * 64 + lane] = bw[i * 64 + lane];
  const uint4* stream = bw + NLT * 64;     // tiles 16..63 (K-tiles 2..7)

  // layer_norm_all affine coeffs, packed f16 (8 gates per lane: n = 0..7)
  u32 lgp[4], lbp[4];
#pragma unroll
  for (int k = 0; k < 4; ++k) {
    int g0 = wid * 128 + (2 * k) * 16 + l4;
    lgp[k] = pkf16(lna_g[g0], lna_g[g0 + 16]);
    lbp[k] = pkf16(lna_b[g0], lna_b[g0 + 16]);
  }
  float lng = 0.f, lnb = 0.f, cx = 0.f;
  if (tid < HH) {
    lng = ln_g[tid]; lnb = ln_b[tid];
    if (t0 == 0) hx16[tid] = (_Float16)0.f;
    else { hx16[tid] = hxst[b * HH + tid]; cx = cxst[b * HH + tid]; }
  }
  __syncthreads();

  const _Float16* xrow = xphf + (size_t)b * GG + wid * 128 + l4 * 8;
  _Float16* hsp = hs16 + (size_t)b * HH + (tid & 255);

  f16x8 xp = *(const f16x8*)xrow;    // 8 n-values for this lane's gates
  for (int tl = 0; tl < ct; ++tl) {
    uint4 s0[8], s1[8];
#pragma unroll
    for (int i = 0; i < 8; ++i) s0[i] = stream[(0 * 8 + i) * 64 + lane];   // K2
#pragma unroll
    for (int i = 0; i < 8; ++i) s1[i] = stream[(1 * 8 + i) * 64 + lane];   // K3

    f32x4 acc[8];
#pragma unroll
    for (int n = 0; n < 8; ++n) acc[n] = (f32x4){0.f, 0.f, 0.f, 0.f};

    // K0, K1 from LDS
#pragma unroll
    for (int t = 0; t < 2; ++t) {
      AFRAG(t);
#pragma unroll
      for (int n = 0; n < 8; ++n) {
        f16x8 bfr = __builtin_bit_cast(f16x8, wl[(wid * NLT + t * 8 + n) * 64 + lane]);
        acc[n] = __builtin_amdgcn_mfma_f32_16x16x32_f16(afr, bfr, acc[n], 0, 0, 0);
      }
    }
    { // K2 from s0; refill s0 <- K4
      AFRAG(2);
#pragma unroll
      for (int n = 0; n < 8; ++n)
        acc[n] = __builtin_amdgcn_mfma_f32_16x16x32_f16(afr, __builtin_bit_cast(f16x8, s0[n]), acc[n], 0, 0, 0);
#pragma unroll
      for (int i = 0; i < 8; ++i) s0[i] = stream[(2 * 8 + i) * 64 + lane];
    }
    { // K3 from s1; refill s1 <- K5
      AFRAG(3);
#pragma unroll
      for (int n = 0; n < 8; ++n)
        acc[n] = __builtin_amdgcn_mfma_f32_16x16x32_f16(afr, __builtin_bit_cast(f16x8, s1[n]), acc[n], 0, 0, 0);
#pragma unroll
      for (int i = 0; i < 8; ++i) s1[i] = stream[(3 * 8 + i) * 64 + lane];
    }
    { // K4 from s0; refill s0 <- K6
      AFRAG(4);
#pragma unroll
      for (int n = 0; n < 8; ++n)
        acc[n] = __builtin_amdgcn_mfma_f32_16x16x32_f16(afr, __builtin_bit_cast(f16x8, s0[n]), acc[n], 0, 0, 0);
#pragma unroll
      for (int i = 0; i < 8; ++i) s0[i] = stream[(4 * 8 + i) * 64 + lane];
    }
    { // K5 from s1; refill s1 <- K7
      AFRAG(5);
#pragma unroll
      for (int n = 0; n < 8; ++n)
        acc[n] = __builtin_amdgcn_mfma_f32_16x16x32_f16(afr, __builtin_bit_cast(f16x8, s1[n]), acc[n], 0, 0, 0);
#pragma unroll
      for (int i = 0; i < 8; ++i) s1[i] = stream[(5 * 8 + i) * 64 + lane];
    }
    { // K6 from s0
      AFRAG(6);
#pragma unroll
      for (int n = 0; n < 8; ++n)
        acc[n] = __builtin_amdgcn_mfma_f32_16x16x32_f16(afr, __builtin_bit_cast(f16x8, s0[n]), acc[n], 0, 0, 0);
    }
    { // K7 from s1
      AFRAG(7);
#pragma unroll
      for (int n = 0; n < 8; ++n)
        acc[n] = __builtin_amdgcn_mfma_f32_16x16x32_f16(afr, __builtin_bit_cast(f16x8, s1[n]), acc[n], 0, 0, 0);
    }

    // gates: lanes 0-15 hold row 0 in acc[n][0]  (v5-verified C/D layout)
    float g8[8];
#pragma unroll
    for (int n = 0; n < 8; ++n) g8[n] = acc[n][0] + (float)xp[n];
    if (tl + 1 < ct) xp = *(const f16x8*)(xrow + (size_t)(tl + 1) * (BB * GG));

    // gate-block LN over 256 gates = waves {2q, 2q+1}; data in lanes 0-15
    float s = 0.f, ss = 0.f;
#pragma unroll
    for (int n = 0; n < 8; ++n) { s += g8[n]; ss += g8[n] * g8[n]; }
#pragma unroll
    for (int m = 1; m <= 8; m <<= 1) {
      s += __shfl_xor(s, m, 64);
      ss += __shfl_xor(ss, m, 64);
    }
    if (lane == 0) { red[wid] = s; red[8 + wid] = ss; }
    __syncthreads();                                  // B1
    float S  = red[2 * q] + red[2 * q + 1];
    float SS = red[8 + 2 * q] + red[8 + 2 * q + 1];
    float mean = S * (1.f / HH);
    float var = SS * (1.f / HH) - mean * mean;
    float rstd = rsqrtf(var + LN_EPS);
    if (lane < 16) {
#pragma unroll
      for (int n = 0; n < 8; ++n) {
        h2 lgv = __builtin_bit_cast(h2, lgp[n >> 1]);
        h2 lbv = __builtin_bit_cast(h2, lbp[n >> 1]);
        float gn = (g8[n] - mean) * rstd * (float)lgv[n & 1] + (float)lbv[n & 1];
        float av = (q == 2) ? fast_tanh(gn) : fast_sigmoid(gn);   // wave-uniform
        gact[wid * 128 + n * 16 + lane] = av;
      }
    }
    __syncthreads();                                  // B2

    float cy = 0.f;
    if (tid < HH) {
      int h = tid;
      cy = gact[HH + h] * cx + gact[h] * gact[2 * HH + h];
      cx = cy;
      float s2 = cy, ss2 = cy * cy;
#pragma unroll
      for (int m = 1; m <= 32; m <<= 1) {
        s2 += __shfl_xor(s2, m, 64);
        ss2 += __shfl_xor(ss2, m, 64);
      }
      if (lane == 0) { red2[wid] = s2; red2[4 + wid] = ss2; }
    }
    __syncthreads();                                  // B3
    if (tid < HH) {
      int h = tid;
      float S2  = red2[0] + red2[1] + red2[2] + red2[3];
      float SS2 = red2[4] + red2[5] + red2[6] + red2[7];
      float mc = S2 * (1.f / HH);
      float vc = SS2 * (1.f / HH) - mc * mc;
      float cyn = (cy - mc) * rsqrtf(vc + LN_EPS) * lng + lnb;
      float hy = gact[3 * HH + h] * fast_tanh(cyn);
      hx16[h] = (_Float16)hy;
      hsp[(size_t)(t0 + tl) * (BB * HH)] = (_Float16)hy;
    }
    __syncthreads();                                  // B4
  }
  if (tid < HH) { hxst[b * HH + tid] = hx16[tid]; cxst[b * HH + tid] = cx; }
}

// ---------------- out GEMM: out[b][t][o] = relu(sum_h hs[t][b][h]*Wf[o][h] + bf[o])
__global__ __launch_bounds__(256) void out_gemm(
    const _Float16* __restrict__ hs16, const float* __restrict__ Wf,
    const float* __restrict__ bf, float* __restrict__ out) {
  __shared__ u32 wfl[128][64];    // pairs [kp][o], 32KB
  __shared__ u32 hsl[16][132];    // pairs [p][kp], padded
  const int tid = threadIdx.x;
  const int mbase = blockIdx.x * 16;
#pragma unroll
  for (int i = 0; i < 32; ++i) {  // 8192 pairs of Wf
    int idx = i * 256 + tid;
    int kp = idx >> 6, o = idx & 63;
    wfl[kp][o] = pkf16(Wf[o * HH + kp * 2], Wf[o * HH + kp * 2 + 1]);
  }
#pragma unroll
  for (int i = 0; i < 8; ++i) {   // 2048 pairs of hs
    int idx = i * 256 + tid;
    int p = idx >> 7, kp = idx & 127;
    hsl[p][kp] = *(const u32*)(hs16 + (size_t)(mbase + p) * HH + kp * 2);
  }
  __syncthreads();
  const int o = tid & 63, mi = tid >> 6;
  float bfo = bf[o];
#pragma unroll
  for (int mm = mi; mm < 16; mm += 4) {
    float a0 = bfo, a1 = 0.f, a2 = 0.f, a3 = 0.f;
#pragma unroll
    for (int kp = 0; kp < 128; kp += 4) {
      a0 = fdot2(wfl[kp + 0][o], hsl[mm][kp + 0], a0);
      a1 = fdot2(wfl[kp + 1][o], hsl[mm][kp + 1], a1);
      a2 = fdot2(wfl[kp + 2][o], hsl[mm][kp + 2], a2);
      a3 = fdot2(wfl[kp + 3][o], hsl[mm][kp + 3], a3);
    }
    float r = (a0 + a1) + (a2 + a3);
    int m = mbase + mm;
    out[(size_t)(m & 63) * (T_TOT * OO) + (size_t)(m >> 6) * OO + o] = fmaxf(r, 0.f);
  }
}

extern "C" void kernel_launch(void* const* d_in, const int* in_sizes, int n_in,
                              void* d_out, int out_size, void* d_ws, size_t ws_size,
                              hipStream_t stream) {
  if (n_in < 11) return;
  const float* x    = (const float*)d_in[0];
  const float* Wi   = (const float*)d_in[1];
  const float* bi   = (const float*)d_in[2];
  const float* Wh   = (const float*)d_in[3];
  const float* bh   = (const float*)d_in[4];
  const float* lnag = (const float*)d_in[5];
  const float* lnab = (const float*)d_in[6];
  const float* lng  = (const float*)d_in[7];
  const float* lnb  = (const float*)d_in[8];
  const float* Wf   = (const float*)d_in[9];
  const float* bf   = (const float*)d_in[10];
  float* out = (float*)d_out;

  char* ws = (char*)d_ws;
  uint4* bfragG = (uint4*)ws;                                // 512 KB
  uint4* wip4 = (uint4*)(ws + (512 << 10));                  // 256 KB
  _Float16* hs16 = (_Float16*)(ws + (1 << 20));              // 32 MB
  _Float16* hxst = (_Float16*)(ws + (1 << 20) + (32 << 20)); // 32 KB
  float* cxst = (float*)(ws + (1 << 20) + (32 << 20) + (64 << 10)); // 64 KB
  const size_t xph_off = (size_t)35 << 20;
  _Float16* xph = (_Float16*)(ws + xph_off);

  size_t avail = ws_size > xph_off ? ws_size - xph_off : 0;
  int ct = T_TOT;
  while (ct > 1 && (size_t)ct * (BB * GG * 2) > avail) ct >>= 1;

  prep_bfrag<<<128, 256, 0, stream>>>(Wh, bfragG);
  prep_wi<<<64, 256, 0, stream>>>(Wi, wip4);
  for (int t0 = 0; t0 < T_TOT; t0 += ct) {
    xproj_gemm<<<dim3((ct * BB) / 16, 4), 256, 0, stream>>>(x, wip4, bi, bh, xph, t0 * BB);
    lstm_scan<<<BB, 512, 0, stream>>>(bfragG, xph, lnag, lnab, lng, lnb,
                                      hs16, hxst, cxst, t0, ct);
  }
  out_gemm<<<(T_TOT * BB) / 16, 256, 0, stream>>>(hs16, Wf, bf, out);
}